// Round 16
// baseline (398.258 us; speedup 1.0000x reference)
//
#include <hip/hip_runtime.h>

// Problem constants
#define NN      81920
#define BB      4096
#define PP      20
#define DD      128
#define DOUTT   256
#define MAXDEGG 8
#define NBLK_H  320   // hist/scatter blocks (320 x 256 = 81920)

using bf16x8 = __attribute__((ext_vector_type(8))) short;
using f32x4  = __attribute__((ext_vector_type(4))) float;
using u16x4  = __attribute__((ext_vector_type(4))) ushort;

__device__ __forceinline__ float b2f(ushort u) {
    union { unsigned u; float f; } v; v.u = ((unsigned)u) << 16; return v.f;
}
__device__ __forceinline__ ushort f2b(float f) {
    union { float f; unsigned u; } v; v.f = f;
    unsigned r = v.u + 0x7fffu + ((v.u >> 16) & 1u);
    return (ushort)(r >> 16);
}
__device__ __forceinline__ float sigm(float x) {
    return __fdividef(1.f, 1.f + __expf(-x));
}
__device__ __forceinline__ float tanh_fast(float x) {
    return 1.f - __fdividef(2.f, 1.f + __expf(2.f * x));
}
__device__ __forceinline__ f32x4 mfma16(bf16x8 a, bf16x8 b, f32x4 c) {
    return __builtin_amdgcn_mfma_f32_16x16x32_bf16(a, b, c, 0, 0, 0);
}
__device__ __forceinline__ bf16x8 pack8(float4 a, float4 b) {
    bf16x8 r;
    r[0] = (short)f2b(a.x); r[1] = (short)f2b(a.y);
    r[2] = (short)f2b(a.z); r[3] = (short)f2b(a.w);
    r[4] = (short)f2b(b.x); r[5] = (short)f2b(b.y);
    r[6] = (short)f2b(b.z); r[7] = (short)f2b(b.w);
    return r;
}
__device__ __forceinline__ bf16x8 ld8_bf(const ushort* p) { return *(const bf16x8*)p; }
__device__ __forceinline__ bf16x8 ld8_f32(const float* p) {
    return pack8(*(const float4*)p, *(const float4*)(p + 4));
}

// ---------------- fused: BN1 stats (blocks 0..639) + degree hist (640..959)
__global__ __launch_bounds__(256) void stats_hist_k(const float* __restrict__ X,
                                                    const int* __restrict__ deg,
                                                    float* __restrict__ part,
                                                    int* __restrict__ blockHist) {
    const int tid = threadIdx.x;
    if (blockIdx.x < 640) {
        const int col  = tid & 127;
        const int half = tid >> 7;
        const long base = (long)blockIdx.x * 128 + (long)half * 64;
        float s = 0.f, q = 0.f;
        for (int i = 0; i < 64; ++i) {
            float x = X[(base + i) * 128 + col];
            s += x; q += x * x;
        }
        __shared__ float red[2][2][128];
        red[0][half][col] = s;
        red[1][half][col] = q;
        __syncthreads();
        if (tid < 128) {
            part[blockIdx.x * 128 + tid]             = red[0][0][tid] + red[0][1][tid];
            part[640 * 128 + blockIdx.x * 128 + tid] = red[1][0][tid] + red[1][1][tid];
        }
    } else {
        __shared__ int wh[4][9];
        const int hb = blockIdx.x - 640;
        const int w = tid >> 6, lane = tid & 63;
        int d = deg[hb * 256 + tid]; d = min(max(d, 0), 8);
#pragma unroll
        for (int c = 0; c < 9; ++c) {
            unsigned long long m = __ballot(d == c);
            if (lane == 0) wh[w][c] = __popcll(m);
        }
        __syncthreads();
        if (tid < 9) {
            int s = 0;
#pragma unroll
            for (int w2 = 0; w2 < 4; ++w2) s += wh[w2][tid];
            blockHist[hb * 9 + tid] = s;
        }
    }
}

// ---------------- fused: bn_final (blocks 0..127, parallel) + scan (block 128)
__global__ __launch_bounds__(256) void bnfinal_scan_k(const float* __restrict__ part, int nparts,
                                                      const float* __restrict__ g,
                                                      const float* __restrict__ b,
                                                      float2* __restrict__ ss,
                                                      const int* __restrict__ blockHist,
                                                      int* __restrict__ blockBase) {
    const int t = threadIdx.x;
    if (blockIdx.x < 128) {
        const int c = blockIdx.x;
        float s = 0.f, q = 0.f;
        for (int i = t; i < nparts; i += 256) {
            s += part[(long)i * 128 + c];
            q += part[(long)(nparts + i) * 128 + c];
        }
#pragma unroll
        for (int off = 32; off > 0; off >>= 1) {
            s += __shfl_xor(s, off, 64);
            q += __shfl_xor(q, off, 64);
        }
        __shared__ float rs[4], rq[4];
        if ((t & 63) == 0) { rs[t >> 6] = s; rq[t >> 6] = q; }
        __syncthreads();
        if (t == 0) {
            s = rs[0] + rs[1] + rs[2] + rs[3];
            q = rq[0] + rq[1] + rq[2] + rq[3];
            const float inv_n = 1.f / (float)NN;
            float mean = s * inv_n;
            float var  = q * inv_n - mean * mean;
            float rstd = rsqrtf(var + 1e-5f);
            float sc = g[c] * rstd;
            ss[c] = make_float2(sc, b[c] - mean * sc);
        }
    } else {
        __shared__ int classTot[9], classStart[9];
        if (t < 9) {
            int s = 0;
            for (int b2 = 0; b2 < NBLK_H; ++b2) s += blockHist[b2 * 9 + t];
            classTot[t] = s;
        }
        __syncthreads();
        if (t == 0) {
            int acc = 0;
            for (int k = 0; k < 9; ++k) { classStart[k] = acc; acc += classTot[k]; }
        }
        __syncthreads();
        if (t < 9) {
            int acc = classStart[t];
            for (int b2 = 0; b2 < NBLK_H; ++b2) {
                blockBase[b2 * 9 + t] = acc;
                acc += blockHist[b2 * 9 + t];
            }
        }
    }
}

// ---------------- scatter: recompute ranks, write perm (atomic-free) -------
__global__ __launch_bounds__(256) void scatter_k(const int* __restrict__ deg,
                                                 const int* __restrict__ blockBase,
                                                 int* __restrict__ perm) {
    __shared__ int wh[4][9];
    __shared__ int wbase[4][9];
    const int t = threadIdx.x, w = t >> 6, lane = t & 63;
    const int i = blockIdx.x * 256 + t;
    int d = deg[i]; d = min(max(d, 0), 8);
    int lt = 0;
#pragma unroll
    for (int c = 0; c < 9; ++c) {
        unsigned long long m = __ballot(d == c);
        if (lane == 0) wh[w][c] = __popcll(m);
        if (d == c) lt = __popcll(m & ((1ull << lane) - 1ull));
    }
    __syncthreads();
    if (t < 36) {
        const int w2 = t / 9, c = t - w2 * 9;
        int s = blockBase[blockIdx.x * 9 + c];
        for (int k = 0; k < w2; ++k) s += wh[k][c];
        wbase[w2][c] = s;
    }
    __syncthreads();
    perm[wbase[w][d] + lt] = i;
}

// ---------------- Generic fused GEMM (NWAVE waves) -------------------------
template <int NCOL, int NWAVE, int KPARTS, bool A1F32, bool GATHER2, bool BIAS1,
          bool BIAS2, bool FOLD1, bool FOLD2, int OUTMODE>
__global__ __launch_bounds__(NWAVE * 64) void gemm_bt(
    const void* __restrict__ A1, const void* __restrict__ A2,
    const float* __restrict__ W1, const float* __restrict__ W2,
    const float* __restrict__ bias1, const float* __restrict__ bias2, int blim,
    const float2* __restrict__ ssW1, const float2* __restrict__ ssW2,
    const int* __restrict__ gidx, void* __restrict__ outv,
    float* __restrict__ part, int nparts) {
    constexpr int JT = NCOL / (16 * NWAVE);  // 16-col tiles per wave
    const int tid = threadIdx.x;
    const int w   = tid >> 6;
    const int l   = tid & 63;
    const int l15 = l & 15;
    const int l4  = l >> 4;
    const int colbase = w * (NCOL / NWAVE);

    bf16x8 bfr[JT][KPARTS * 4];
    float bv[JT];
#pragma unroll
    for (int jl = 0; jl < JT; ++jl) {
        const int wrow = colbase + jl * 16 + l15;
        float fb = 0.f;
#pragma unroll
        for (int kp = 0; kp < KPARTS; ++kp) {
            const float* Wp = (kp == 0) ? W1 : W2;
            const float2* sp = (kp == 0) ? ssW1 : ssW2;
            const bool fold = (kp == 0) ? FOLD1 : FOLD2;
#pragma unroll
            for (int kt = 0; kt < 4; ++kt) {
                const float* wp = &Wp[(long)wrow * 128 + kt * 32 + l4 * 8];
                float4 a = *(const float4*)wp;
                float4 b4 = *(const float4*)(wp + 4);
                if (fold) {
                    const float* s = (const float*)(sp + kt * 32 + l4 * 8);
                    float4 s0 = *(const float4*)s, s1 = *(const float4*)(s + 4);
                    float4 s2 = *(const float4*)(s + 8), s3 = *(const float4*)(s + 12);
                    fb += s0.y * a.x + s0.w * a.y + s1.y * a.z + s1.w * a.w
                        + s2.y * b4.x + s2.w * b4.y + s3.y * b4.z + s3.w * b4.w;
                    a.x *= s0.x; a.y *= s0.z; a.z *= s1.x; a.w *= s1.z;
                    b4.x *= s2.x; b4.y *= s2.z; b4.z *= s3.x; b4.w *= s3.z;
                }
                bfr[jl][kp * 4 + kt] = pack8(a, b4);
            }
        }
        if (FOLD1 || FOLD2) {
            fb += __shfl_xor(fb, 16, 64);
            fb += __shfl_xor(fb, 32, 64);
        }
        if (BIAS1) fb += bias1[wrow];
        if (BIAS2) fb += (wrow < blim) ? bias2[wrow] : 0.f;
        bv[jl] = fb;
    }

    const int rowblk = blockIdx.x * 64;
    const f32x4 fz = {0.f, 0.f, 0.f, 0.f};
    float ssum[JT], sq[JT];
#pragma unroll
    for (int jl = 0; jl < JT; ++jl) { ssum[jl] = 0.f; sq[jl] = 0.f; }

#pragma unroll
    for (int it = 0; it < 4; ++it) {
        const int arow1 = rowblk + it * 16 + l15;
        bf16x8 afr[KPARTS * 4];
#pragma unroll
        for (int kt = 0; kt < 4; ++kt) {
            if (A1F32)
                afr[kt] = ld8_f32(&((const float*)A1)[(long)arow1 * 128 + kt * 32 + l4 * 8]);
            else
                afr[kt] = ld8_bf(&((const ushort*)A1)[(long)arow1 * 128 + kt * 32 + l4 * 8]);
        }
        if (KPARTS == 2) {
            const long arow2 = GATHER2 ? (long)gidx[arow1] : (long)arow1;
#pragma unroll
            for (int kt = 0; kt < 4; ++kt)
                afr[4 + kt] = ld8_bf(&((const ushort*)A2)[arow2 * 128 + kt * 32 + l4 * 8]);
        }
        f32x4 acc[JT];
#pragma unroll
        for (int jl = 0; jl < JT; ++jl) {
            acc[jl] = fz;
#pragma unroll
            for (int kk = 0; kk < KPARTS * 4; ++kk)
                acc[jl] = mfma16(afr[kk], bfr[jl][kk], acc[jl]);
        }
#pragma unroll
        for (int jl = 0; jl < JT; ++jl) {
            const int col = colbase + jl * 16 + l15;
#pragma unroll
            for (int r = 0; r < 4; ++r) {
                const long orow = rowblk + it * 16 + l4 * 4 + r;
                float v = acc[jl][r] + bv[jl];
                if (OUTMODE == 0 || OUTMODE == 2)
                    ((ushort*)outv)[orow * NCOL + col] = f2b(v);
                if (OUTMODE == 1)
                    ((float*)outv)[orow * NCOL + col] = v;
                if (OUTMODE == 2) { ssum[jl] += v; sq[jl] += v * v; }
            }
        }
    }
    if (OUTMODE == 2) {
#pragma unroll
        for (int jl = 0; jl < JT; ++jl) {
            float s = ssum[jl], q = sq[jl];
            s += __shfl_xor(s, 16, 64); s += __shfl_xor(s, 32, 64);
            q += __shfl_xor(q, 16, 64); q += __shfl_xor(q, 32, 64);
            if (l4 == 0) {
                const int col = colbase + jl * 16 + l15;
                part[(long)blockIdx.x * 128 + col] = s;
                part[(long)nparts * 128 + (long)blockIdx.x * 128 + col] = q;
            }
        }
    }
}

// ---------------- Fused ragged GRU, degree-sorted blocks -------------------
// R16: 128 nodes/block (grid 640). Halves per-block fixed costs (W_hh L2
// traffic 251->125MB, zero-init, ramps) and barrier count per node-step.
// LDS 74.7KB -> 2 blocks/CU; 16 waves/CU means up to 128 VGPR/wave is free,
// so the deeper in-step prefetch (6 q-groups live) fits without the cliff.
// (R14 measured the inverse: 32-node blocks doubled fixed costs, +13us.)
#define GLOAD(d0, d1, d2, ROW, TT)                                 \
    { const ushort* Gp_ = G + (long)nbrs[ROW][TT] * 384;           \
      d0 = *(const u16x4*)&Gp_[c0];                                \
      d1 = *(const u16x4*)&Gp_[c0 + 128];                          \
      d2 = *(const u16x4*)&Gp_[c0 + 256]; }

#define GRU_STEP(IT, Gv0, Gv1, Gv2)                                         \
    {                                                                       \
        const int row_ = (IT) * 16 + l15;                                   \
        const bool upd_ = (t < dreg[IT]);                                   \
        bf16x8 af0 = *(const bf16x8*)&hbuf[cur][row_][0 * 32 + l4 * 8];     \
        bf16x8 af1 = *(const bf16x8*)&hbuf[cur][row_][1 * 32 + l4 * 8];     \
        bf16x8 af2 = *(const bf16x8*)&hbuf[cur][row_][2 * 32 + l4 * 8];     \
        bf16x8 af3 = *(const bf16x8*)&hbuf[cur][row_][3 * 32 + l4 * 8];     \
        f32x4 ar = fz, az = fz, an = fz;                                    \
        ar = mfma16(bfr[0][0], af0, ar); az = mfma16(bfr[1][0], af0, az);   \
        an = mfma16(bfr[2][0], af0, an);                                    \
        ar = mfma16(bfr[0][1], af1, ar); az = mfma16(bfr[1][1], af1, az);   \
        an = mfma16(bfr[2][1], af1, an);                                    \
        ar = mfma16(bfr[0][2], af2, ar); az = mfma16(bfr[1][2], af2, az);   \
        an = mfma16(bfr[2][2], af2, an);                                    \
        ar = mfma16(bfr[0][3], af3, ar); az = mfma16(bfr[1][3], af3, az);   \
        an = mfma16(bfr[2][3], af3, an);                                    \
        const u16x4 hold_ = *(const u16x4*)&hbuf[cur][row_][c0];            \
        u16x4 hnew_;                                                        \
        _Pragma("unroll")                                                   \
        for (int r = 0; r < 4; ++r) {                                       \
            const float rr = sigm(b2f(Gv0[r]) + ar[r]);                     \
            const float zz = sigm(b2f(Gv1[r]) + az[r]);                     \
            const float nn = tanh_fast(b2f(Gv2[r]) + rr * (an[r] + bnN[r]));\
            const float hv = (1.f - zz) * nn + zz * b2f(hold_[r]);          \
            hnew_[r] = upd_ ? f2b(hv) : hold_[r];                           \
        }                                                                   \
        *(u16x4*)&hbuf[1 - cur][row_][c0] = hnew_;                          \
    }

__global__ __attribute__((amdgpu_flat_work_group_size(512, 512), amdgpu_waves_per_eu(4, 8)))
void gru_kernel(const ushort* __restrict__ G,
                const float* __restrict__ Whh,
                const float* __restrict__ bhh,
                const int* __restrict__ nbr_idx,
                const int* __restrict__ deg,
                const int* __restrict__ perm,
                ushort* __restrict__ neigh) {
    __shared__ alignas(16) ushort hbuf[2][128][136];
    __shared__ alignas(16) int nbrs[128][8];
    __shared__ int degs[128];
    __shared__ int nid[128];

    const int tid = threadIdx.x;
    const int l   = tid & 63;
    const int l15 = l & 15;
    const int l4  = l >> 4;
    const int blockRow = (gridDim.x - 1 - blockIdx.x) * 128;  // high-deg first
    const int colbase = (tid >> 6) * 16;
    const int c0 = colbase + l4 * 4;

    if (tid < 128) nid[tid] = perm[blockRow + tid];
    {
        bf16x8 z = {0, 0, 0, 0, 0, 0, 0, 0};
        bf16x8* p = (bf16x8*)&hbuf[0][0][0];
        for (int i = tid; i < 128 * 136 / 8; i += 512) p[i] = z;
    }
    __syncthreads();
    for (int i = tid; i < 128 * 8; i += 512)
        nbrs[i >> 3][i & 7] = nbr_idx[(long)nid[i >> 3] * 8 + (i & 7)];
    if (tid < 128) degs[tid] = deg[nid[tid]];

    bf16x8 bfr[3][4];
#pragma unroll
    for (int g = 0; g < 3; ++g)
#pragma unroll
        for (int kt = 0; kt < 4; ++kt)
            bfr[g][kt] = ld8_f32(&Whh[(long)(g * 128 + colbase + l15) * 128 + kt * 32 + l4 * 8]);
    const f32x4 bnN = *(const f32x4*)&bhh[256 + c0];  // n-gate bias only
    __syncthreads();

    int dreg[8];
#pragma unroll
    for (int it = 0; it < 8; ++it) dreg[it] = degs[it * 16 + l15];
    int dmax = max(degs[l], degs[64 + l]);
#pragma unroll
    for (int off = 32; off > 0; off >>= 1) dmax = max(dmax, __shfl_xor(dmax, off, 64));
    dmax = __builtin_amdgcn_readfirstlane(dmax);

    const f32x4 fz = {0.f, 0.f, 0.f, 0.f};
    u16x4 p00, p01, p02, p10, p11, p12;
    GLOAD(p00, p01, p02, l15, 0);
    GLOAD(p10, p11, p12, 16 + l15, 0);

    int cur = 0;
    for (int t = 0; t < dmax; ++t) {
        u16x4 g20, g21, g22, g30, g31, g32, g40, g41, g42;
        u16x4 g50, g51, g52, g60, g61, g62, g70, g71, g72;
        GLOAD(g20, g21, g22,  32 + l15, t);
        GLOAD(g30, g31, g32,  48 + l15, t);
        GLOAD(g40, g41, g42,  64 + l15, t);
        GLOAD(g50, g51, g52,  80 + l15, t);
        GLOAD(g60, g61, g62,  96 + l15, t);
        GLOAD(g70, g71, g72, 112 + l15, t);
        GRU_STEP(0, p00, p01, p02);
        GRU_STEP(1, p10, p11, p12);
        if (t + 1 < dmax) {  // wave-uniform: skip dead last-step prefetch
            GLOAD(p00, p01, p02, l15, t + 1);
            GLOAD(p10, p11, p12, 16 + l15, t + 1);
        }
        GRU_STEP(2, g20, g21, g22);
        GRU_STEP(3, g30, g31, g32);
        GRU_STEP(4, g40, g41, g42);
        GRU_STEP(5, g50, g51, g52);
        GRU_STEP(6, g60, g61, g62);
        GRU_STEP(7, g70, g71, g72);
        __syncthreads();
        cur ^= 1;
    }
    for (int idx = tid; idx < 128 * 16; idx += 512) {
        const int row = idx >> 4, ch = idx & 15;
        bf16x8* dst = (bf16x8*)(neigh + (long)nid[row] * 128);
        dst[ch] = *(const bf16x8*)&hbuf[cur][row][ch * 8];
    }
}

// ---------------- fused e + softmax + segment sums -------------------------
// 1024 blocks x 256 thr (4 waves); block = 4 graphs = 80 rows.
__global__ __launch_bounds__(256) void seg_e_k(const ushort* __restrict__ rst,
                                               const float* __restrict__ Wu,
                                               const float2* __restrict__ ss2,
                                               const float* __restrict__ fvl,
                                               const float* __restrict__ We,
                                               const float* __restrict__ pw,
                                               ushort* __restrict__ s12) {
    __shared__ float epart[4][80];
    __shared__ float ash[80];
    const int tid = threadIdx.x;
    const int w   = tid >> 6;
    const int l   = tid & 63;
    const int l15 = l & 15;
    const int l4  = l >> 4;
    const int colbase = w * 32;
    const int rowblk = blockIdx.x * 80;

    bf16x8 bfr[2][4];
    float bv[2], Wec[2];
#pragma unroll
    for (int jl = 0; jl < 2; ++jl) {
        const int wrow = colbase + jl * 16 + l15;
        float fb = 0.f;
#pragma unroll
        for (int kt = 0; kt < 4; ++kt) {
            const float* wp = &Wu[(long)wrow * 128 + kt * 32 + l4 * 8];
            float4 a = *(const float4*)wp;
            float4 b4 = *(const float4*)(wp + 4);
            const float* s = (const float*)(ss2 + kt * 32 + l4 * 8);
            float4 s0 = *(const float4*)s, s1 = *(const float4*)(s + 4);
            float4 s2 = *(const float4*)(s + 8), s3 = *(const float4*)(s + 12);
            fb += s0.y * a.x + s0.w * a.y + s1.y * a.z + s1.w * a.w
                + s2.y * b4.x + s2.w * b4.y + s3.y * b4.z + s3.w * b4.w;
            a.x *= s0.x; a.y *= s0.z; a.z *= s1.x; a.w *= s1.z;
            b4.x *= s2.x; b4.y *= s2.z; b4.z *= s3.x; b4.w *= s3.z;
            bfr[jl][kt] = pack8(a, b4);
        }
        fb += __shfl_xor(fb, 16, 64);
        fb += __shfl_xor(fb, 32, 64);
        bv[jl] = fb;
        Wec[jl] = We[wrow];
    }

    const f32x4 fz = {0.f, 0.f, 0.f, 0.f};
#pragma unroll
    for (int it = 0; it < 5; ++it) {
        const int arow = rowblk + it * 16 + l15;
        bf16x8 afr[4];
#pragma unroll
        for (int kt = 0; kt < 4; ++kt)
            afr[kt] = ld8_bf(&rst[(long)arow * 128 + kt * 32 + l4 * 8]);
        f32x4 acc[2];
#pragma unroll
        for (int jl = 0; jl < 2; ++jl) {
            acc[jl] = fz;
#pragma unroll
            for (int kt = 0; kt < 4; ++kt)
                acc[jl] = mfma16(afr[kt], bfr[jl][kt], acc[jl]);
        }
        float ps[4] = {0.f, 0.f, 0.f, 0.f};
#pragma unroll
        for (int jl = 0; jl < 2; ++jl) {
            const int col = colbase + jl * 16 + l15;
#pragma unroll
            for (int r = 0; r < 4; ++r) {
                const long orow = rowblk + it * 16 + l4 * 4 + r;
                const float v = acc[jl][r] + bv[jl];
                const int bg = (int)orow / PP;
                ps[r] += sigm(v + fvl[(long)bg * 128 + col]) * Wec[jl];
            }
        }
#pragma unroll
        for (int r = 0; r < 4; ++r) {
#pragma unroll
            for (int off = 1; off < 16; off <<= 1)
                ps[r] += __shfl_xor(ps[r], off, 64);
        }
        if (l15 == 0) {
#pragma unroll
            for (int r = 0; r < 4; ++r)
                epart[w][it * 16 + l4 * 4 + r] = ps[r];
        }
    }
    __syncthreads();
    if (tid < 80)
        ash[tid] = epart[0][tid] + epart[1][tid] + epart[2][tid] + epart[3][tid];
    __syncthreads();
    if (tid < 4) {
        const int o = tid * PP;
        float m = -1e30f;
        for (int p = 0; p < PP; ++p) m = fmaxf(m, ash[o + p]);
        float sum = 0.f;
        for (int p = 0; p < PP; ++p) { ash[o + p] = __expf(ash[o + p] - m); sum += ash[o + p]; }
        const float inv = __fdividef(1.f, sum);
        for (int p = 0; p < PP; ++p) ash[o + p] *= inv;
    }
    __syncthreads();
    const int c = tid & 127;
    const float2 sc2 = ss2[c];
#pragma unroll
    for (int pass = 0; pass < 2; ++pass) {
        const int gl = pass * 2 + (tid >> 7);
        const int g = blockIdx.x * 4 + gl;
        float a1 = 0.f, a2 = 0.f;
#pragma unroll
        for (int p = 0; p < PP; ++p) {
            const int node = g * PP + p;
            const float hv = b2f(rst[(long)node * 128 + c]) * sc2.x + sc2.y;
            a1 += ash[gl * PP + p] * hv;
            a2 += pw[node] * hv;
        }
        s12[(long)g * 128 + c]        = f2b(a1);
        s12[(long)(BB + g) * 128 + c] = f2b(a2);
    }
}

// ---------------------------------------------------------------------------
extern "C" void kernel_launch(void* const* d_in, const int* in_sizes, int n_in,
                              void* d_out, int out_size, void* d_ws, size_t ws_size,
                              hipStream_t stream) {
    const float* feat    = (const float*)d_in[0];
    const float* intend  = (const float*)d_in[1];
    const float* pw      = (const float*)d_in[2];
    const int*   nbr_idx = (const int*)d_in[3];
    const int*   deg     = (const int*)d_in[4];
    const int*   last    = (const int*)d_in[5];
    const float* bn1_g   = (const float*)d_in[6];
    const float* bn1_b   = (const float*)d_in[7];
    const float* W_ih    = (const float*)d_in[8];
    const float* W_hh    = (const float*)d_in[9];
    const float* b_ih    = (const float*)d_in[10];
    const float* b_hh    = (const float*)d_in[11];
    const float* W_self  = (const float*)d_in[12];
    const float* W_neigh = (const float*)d_in[13];
    const float* bn2_g   = (const float*)d_in[14];
    const float* bn2_b   = (const float*)d_in[15];
    const float* Wu      = (const float*)d_in[16];
    const float* Wv      = (const float*)d_in[17];
    const float* bv      = (const float*)d_in[18];
    const float* Wi      = (const float*)d_in[19];
    const float* bi      = (const float*)d_in[20];
    const float* We      = (const float*)d_in[21];
    const float* Wout    = (const float*)d_in[22];
    float* out = (float*)d_out;
    char* ws = (char*)d_ws;

    // workspace layout (bytes)
    ushort* G     = (ushort*)(ws + 0L);              // 62,914,560  [N,384] bf16
    ushort* rst   = G;                               // alias (G dead after gru)
    ushort* neigh = (ushort*)(ws + 62914560L);       // 20,971,520
    float*  fvl   = (float*)(ws + 83886080L);        // 2,097,152
    ushort* s12   = (ushort*)(ws + 86310912L);       // 2,097,152
    float*  part1 = (float*)(ws + 88408064L);        // 655,360
    float*  part2 = (float*)(ws + 89063424L);        // 1,310,720
    int*    perm  = (int*)(ws + 90374144L);          // 327,680
    float2* ss1   = (float2*)(ws + 90701824L);       // 1,024
    float2* ss2   = (float2*)(ws + 90702848L);       // 1,024
    int*    blockHist = (int*)(ws + 90703872L);      // 320*9*4 = 11,520
    int*    blockBase = (int*)(ws + 90715392L);      // 11,520

    // ---- BN1 stats + degree hist (fused) ----
    stats_hist_k<<<960, 256, 0, stream>>>(feat, deg, part1, blockHist);
    // ---- BN1 finalize + bucket scan (fused) ----
    bnfinal_scan_k<<<129, 256, 0, stream>>>(part1, 640, bn1_g, bn1_b, ss1,
                                            blockHist, blockBase);
    // ---- scatter -> perm ----
    scatter_k<<<NBLK_H, 256, 0, stream>>>(deg, blockBase, perm);

    // ---- G = bn1(feat)@W_ih.T + b_ih + b_hh[rz-fold]  (4-wave, JT=6) ----
    gemm_bt<384, 4, 1, true, false, true, true, true, false, 0><<<1280, 256, 0, stream>>>(
        feat, nullptr, W_ih, nullptr, b_ih, b_hh, 256, ss1, nullptr,
        nullptr, G, nullptr, 0);

    // ---- ragged GRU (degree-sorted, high-deg first, 128 nodes/block) ----
    gru_kernel<<<640, 512, 0, stream>>>(G, W_hh, b_hh, nbr_idx, deg, perm, neigh);

    // ---- rst = bn1(feat)@W_self.T + neigh@W_neigh.T  (+BN2-stats epilogue) ----
    gemm_bt<128, 4, 2, true, false, false, false, true, false, 2><<<1280, 256, 0, stream>>>(
        feat, neigh, W_self, W_neigh, nullptr, nullptr, 0, ss1, nullptr,
        nullptr, rst, part2, 1280);
    bnfinal_scan_k<<<128, 256, 0, stream>>>(part2, 1280, bn2_g, bn2_b, ss2,
                                            nullptr, nullptr);

    // ---- fvl = intend@Wv.T + bv + bn2(rst)[last]@Wi.T + bi  (f32) ----
    gemm_bt<128, 4, 2, true, true, true, true, false, true, 1><<<64, 256, 0, stream>>>(
        intend, rst, Wv, Wi, bv, bi, 128, nullptr, ss2,
        last, fvl, nullptr, 0);

    // ---- fused e + softmax + segment sums -> s12 ----
    seg_e_k<<<1024, 256, 0, stream>>>(rst, Wu, ss2, fvl, We, pw, s12);

    // ---- [rst_g; pos] = s12 @ Wout.T -> d_out (f32) ----
    gemm_bt<256, 4, 1, false, false, false, false, false, false, 1><<<128, 256, 0, stream>>>(
        s12, nullptr, Wout, nullptr, nullptr, nullptr, 0, nullptr, nullptr,
        nullptr, out, nullptr, 0);

    (void)in_sizes; (void)n_in; (void)out_size; (void)ws_size;
}

// Round 17
// 325.523 us; speedup vs baseline: 1.2234x; 1.2234x over previous
//
#include <hip/hip_runtime.h>

// Problem constants
#define NN      81920
#define BB      4096
#define PP      20
#define DD      128
#define DOUTT   256
#define MAXDEGG 8
#define NBLK_H  320   // hist/scatter blocks (320 x 256 = 81920)

using bf16x8 = __attribute__((ext_vector_type(8))) short;
using f32x4  = __attribute__((ext_vector_type(4))) float;
using u16x4  = __attribute__((ext_vector_type(4))) ushort;

__device__ __forceinline__ float b2f(ushort u) {
    union { unsigned u; float f; } v; v.u = ((unsigned)u) << 16; return v.f;
}
__device__ __forceinline__ ushort f2b(float f) {
    union { float f; unsigned u; } v; v.f = f;
    unsigned r = v.u + 0x7fffu + ((v.u >> 16) & 1u);
    return (ushort)(r >> 16);
}
__device__ __forceinline__ float sigm(float x) {
    return __fdividef(1.f, 1.f + __expf(-x));
}
__device__ __forceinline__ float tanh_fast(float x) {
    return 1.f - __fdividef(2.f, 1.f + __expf(2.f * x));
}
__device__ __forceinline__ f32x4 mfma16(bf16x8 a, bf16x8 b, f32x4 c) {
    return __builtin_amdgcn_mfma_f32_16x16x32_bf16(a, b, c, 0, 0, 0);
}
__device__ __forceinline__ bf16x8 pack8(float4 a, float4 b) {
    bf16x8 r;
    r[0] = (short)f2b(a.x); r[1] = (short)f2b(a.y);
    r[2] = (short)f2b(a.z); r[3] = (short)f2b(a.w);
    r[4] = (short)f2b(b.x); r[5] = (short)f2b(b.y);
    r[6] = (short)f2b(b.z); r[7] = (short)f2b(b.w);
    return r;
}
__device__ __forceinline__ bf16x8 ld8_bf(const ushort* p) { return *(const bf16x8*)p; }
__device__ __forceinline__ bf16x8 ld8_f32(const float* p) {
    return pack8(*(const float4*)p, *(const float4*)(p + 4));
}

// ---------------- fused: BN1 stats (blocks 0..639) + degree hist (640..959)
__global__ __launch_bounds__(256) void stats_hist_k(const float* __restrict__ X,
                                                    const int* __restrict__ deg,
                                                    float* __restrict__ part,
                                                    int* __restrict__ blockHist) {
    const int tid = threadIdx.x;
    if (blockIdx.x < 640) {
        const int col  = tid & 127;
        const int half = tid >> 7;
        const long base = (long)blockIdx.x * 128 + (long)half * 64;
        float s = 0.f, q = 0.f;
        for (int i = 0; i < 64; ++i) {
            float x = X[(base + i) * 128 + col];
            s += x; q += x * x;
        }
        __shared__ float red[2][2][128];
        red[0][half][col] = s;
        red[1][half][col] = q;
        __syncthreads();
        if (tid < 128) {
            part[blockIdx.x * 128 + tid]             = red[0][0][tid] + red[0][1][tid];
            part[640 * 128 + blockIdx.x * 128 + tid] = red[1][0][tid] + red[1][1][tid];
        }
    } else {
        __shared__ int wh[4][9];
        const int hb = blockIdx.x - 640;
        const int w = tid >> 6, lane = tid & 63;
        int d = deg[hb * 256 + tid]; d = min(max(d, 0), 8);
#pragma unroll
        for (int c = 0; c < 9; ++c) {
            unsigned long long m = __ballot(d == c);
            if (lane == 0) wh[w][c] = __popcll(m);
        }
        __syncthreads();
        if (tid < 9) {
            int s = 0;
#pragma unroll
            for (int w2 = 0; w2 < 4; ++w2) s += wh[w2][tid];
            blockHist[hb * 9 + tid] = s;
        }
    }
}

// ---------------- fused: bn_final (blocks 0..127, parallel) + scan (block 128)
__global__ __launch_bounds__(256) void bnfinal_scan_k(const float* __restrict__ part, int nparts,
                                                      const float* __restrict__ g,
                                                      const float* __restrict__ b,
                                                      float2* __restrict__ ss,
                                                      const int* __restrict__ blockHist,
                                                      int* __restrict__ blockBase) {
    const int t = threadIdx.x;
    if (blockIdx.x < 128) {
        const int c = blockIdx.x;
        float s = 0.f, q = 0.f;
        for (int i = t; i < nparts; i += 256) {
            s += part[(long)i * 128 + c];
            q += part[(long)(nparts + i) * 128 + c];
        }
#pragma unroll
        for (int off = 32; off > 0; off >>= 1) {
            s += __shfl_xor(s, off, 64);
            q += __shfl_xor(q, off, 64);
        }
        __shared__ float rs[4], rq[4];
        if ((t & 63) == 0) { rs[t >> 6] = s; rq[t >> 6] = q; }
        __syncthreads();
        if (t == 0) {
            s = rs[0] + rs[1] + rs[2] + rs[3];
            q = rq[0] + rq[1] + rq[2] + rq[3];
            const float inv_n = 1.f / (float)NN;
            float mean = s * inv_n;
            float var  = q * inv_n - mean * mean;
            float rstd = rsqrtf(var + 1e-5f);
            float sc = g[c] * rstd;
            ss[c] = make_float2(sc, b[c] - mean * sc);
        }
    } else {
        __shared__ int classTot[9], classStart[9];
        if (t < 9) {
            int s = 0;
            for (int b2 = 0; b2 < NBLK_H; ++b2) s += blockHist[b2 * 9 + t];
            classTot[t] = s;
        }
        __syncthreads();
        if (t == 0) {
            int acc = 0;
            for (int k = 0; k < 9; ++k) { classStart[k] = acc; acc += classTot[k]; }
        }
        __syncthreads();
        if (t < 9) {
            int acc = classStart[t];
            for (int b2 = 0; b2 < NBLK_H; ++b2) {
                blockBase[b2 * 9 + t] = acc;
                acc += blockHist[b2 * 9 + t];
            }
        }
    }
}

// ---------------- scatter: recompute ranks, write perm (atomic-free) -------
__global__ __launch_bounds__(256) void scatter_k(const int* __restrict__ deg,
                                                 const int* __restrict__ blockBase,
                                                 int* __restrict__ perm) {
    __shared__ int wh[4][9];
    __shared__ int wbase[4][9];
    const int t = threadIdx.x, w = t >> 6, lane = t & 63;
    const int i = blockIdx.x * 256 + t;
    int d = deg[i]; d = min(max(d, 0), 8);
    int lt = 0;
#pragma unroll
    for (int c = 0; c < 9; ++c) {
        unsigned long long m = __ballot(d == c);
        if (lane == 0) wh[w][c] = __popcll(m);
        if (d == c) lt = __popcll(m & ((1ull << lane) - 1ull));
    }
    __syncthreads();
    if (t < 36) {
        const int w2 = t / 9, c = t - w2 * 9;
        int s = blockBase[blockIdx.x * 9 + c];
        for (int k = 0; k < w2; ++k) s += wh[k][c];
        wbase[w2][c] = s;
    }
    __syncthreads();
    perm[wbase[w][d] + lt] = i;
}

// ---------------- Generic fused GEMM (NWAVE waves) -------------------------
// out[m,c] = sum_k A1[m,k]W1'[c,k] + (KPARTS==2) A2[m2,k]W2'[c,k] + biases
// ALL GEMMs at NWAVE=4 (R8/R11-proven config; 8-wave measured slower).
// FOLDx: W' = sc*W folded at load; fold-bias = sum_k sh[k]W[c,k] via shfl.
// bias2 applies only to cols < blim (folds b_hh r/z gates into G).
// OUTMODE: 0=bf16 out, 1=f32 out, 2=bf16 out + BN-stats partials
template <int NCOL, int NWAVE, int KPARTS, bool A1F32, bool GATHER2, bool BIAS1,
          bool BIAS2, bool FOLD1, bool FOLD2, int OUTMODE>
__global__ __launch_bounds__(NWAVE * 64) void gemm_bt(
    const void* __restrict__ A1, const void* __restrict__ A2,
    const float* __restrict__ W1, const float* __restrict__ W2,
    const float* __restrict__ bias1, const float* __restrict__ bias2, int blim,
    const float2* __restrict__ ssW1, const float2* __restrict__ ssW2,
    const int* __restrict__ gidx, void* __restrict__ outv,
    float* __restrict__ part, int nparts) {
    constexpr int JT = NCOL / (16 * NWAVE);  // 16-col tiles per wave
    const int tid = threadIdx.x;
    const int w   = tid >> 6;
    const int l   = tid & 63;
    const int l15 = l & 15;
    const int l4  = l >> 4;
    const int colbase = w * (NCOL / NWAVE);

    bf16x8 bfr[JT][KPARTS * 4];
    float bv[JT];
#pragma unroll
    for (int jl = 0; jl < JT; ++jl) {
        const int wrow = colbase + jl * 16 + l15;
        float fb = 0.f;
#pragma unroll
        for (int kp = 0; kp < KPARTS; ++kp) {
            const float* Wp = (kp == 0) ? W1 : W2;
            const float2* sp = (kp == 0) ? ssW1 : ssW2;
            const bool fold = (kp == 0) ? FOLD1 : FOLD2;
#pragma unroll
            for (int kt = 0; kt < 4; ++kt) {
                const float* wp = &Wp[(long)wrow * 128 + kt * 32 + l4 * 8];
                float4 a = *(const float4*)wp;
                float4 b4 = *(const float4*)(wp + 4);
                if (fold) {
                    const float* s = (const float*)(sp + kt * 32 + l4 * 8);
                    float4 s0 = *(const float4*)s, s1 = *(const float4*)(s + 4);
                    float4 s2 = *(const float4*)(s + 8), s3 = *(const float4*)(s + 12);
                    fb += s0.y * a.x + s0.w * a.y + s1.y * a.z + s1.w * a.w
                        + s2.y * b4.x + s2.w * b4.y + s3.y * b4.z + s3.w * b4.w;
                    a.x *= s0.x; a.y *= s0.z; a.z *= s1.x; a.w *= s1.z;
                    b4.x *= s2.x; b4.y *= s2.z; b4.z *= s3.x; b4.w *= s3.z;
                }
                bfr[jl][kp * 4 + kt] = pack8(a, b4);
            }
        }
        if (FOLD1 || FOLD2) {
            fb += __shfl_xor(fb, 16, 64);
            fb += __shfl_xor(fb, 32, 64);
        }
        if (BIAS1) fb += bias1[wrow];
        if (BIAS2) fb += (wrow < blim) ? bias2[wrow] : 0.f;
        bv[jl] = fb;
    }

    const int rowblk = blockIdx.x * 64;
    const f32x4 fz = {0.f, 0.f, 0.f, 0.f};
    float ssum[JT], sq[JT];
#pragma unroll
    for (int jl = 0; jl < JT; ++jl) { ssum[jl] = 0.f; sq[jl] = 0.f; }

#pragma unroll
    for (int it = 0; it < 4; ++it) {
        const int arow1 = rowblk + it * 16 + l15;
        bf16x8 afr[KPARTS * 4];
#pragma unroll
        for (int kt = 0; kt < 4; ++kt) {
            if (A1F32)
                afr[kt] = ld8_f32(&((const float*)A1)[(long)arow1 * 128 + kt * 32 + l4 * 8]);
            else
                afr[kt] = ld8_bf(&((const ushort*)A1)[(long)arow1 * 128 + kt * 32 + l4 * 8]);
        }
        if (KPARTS == 2) {
            const long arow2 = GATHER2 ? (long)gidx[arow1] : (long)arow1;
#pragma unroll
            for (int kt = 0; kt < 4; ++kt)
                afr[4 + kt] = ld8_bf(&((const ushort*)A2)[arow2 * 128 + kt * 32 + l4 * 8]);
        }
        f32x4 acc[JT];
#pragma unroll
        for (int jl = 0; jl < JT; ++jl) {
            acc[jl] = fz;
#pragma unroll
            for (int kk = 0; kk < KPARTS * 4; ++kk)
                acc[jl] = mfma16(afr[kk], bfr[jl][kk], acc[jl]);
        }
#pragma unroll
        for (int jl = 0; jl < JT; ++jl) {
            const int col = colbase + jl * 16 + l15;
#pragma unroll
            for (int r = 0; r < 4; ++r) {
                const long orow = rowblk + it * 16 + l4 * 4 + r;
                float v = acc[jl][r] + bv[jl];
                if (OUTMODE == 0 || OUTMODE == 2)
                    ((ushort*)outv)[orow * NCOL + col] = f2b(v);
                if (OUTMODE == 1)
                    ((float*)outv)[orow * NCOL + col] = v;
                if (OUTMODE == 2) { ssum[jl] += v; sq[jl] += v * v; }
            }
        }
    }
    if (OUTMODE == 2) {
#pragma unroll
        for (int jl = 0; jl < JT; ++jl) {
            float s = ssum[jl], q = sq[jl];
            s += __shfl_xor(s, 16, 64); s += __shfl_xor(s, 32, 64);
            q += __shfl_xor(q, 16, 64); q += __shfl_xor(q, 32, 64);
            if (l4 == 0) {
                const int col = colbase + jl * 16 + l15;
                part[(long)blockIdx.x * 128 + col] = s;
                part[(long)nparts * 128 + (long)blockIdx.x * 128 + col] = q;
            }
        }
    }
}

// ---------------- Fused ragged GRU, degree-sorted blocks -------------------
// FINAL (R13/R15 measured optimum, 128us): 64 nodes/block x 8 waves; wave
// owns 16 cols; swapped MFMA so each lane's 4 gate-cols are contiguous (8B
// G-gathers); named-scalar prefetch with wave-uniform last-step guard; b_hh
// r/z folded into G upstream. Block-size 32 (141us) and 128 (199us, VGPR
// spills at the allocator's immovable 64-reg choice) both measured worse.
#define GLOAD(d0, d1, d2, ROW, TT)                                 \
    { const ushort* Gp_ = G + (long)nbrs[ROW][TT] * 384;           \
      d0 = *(const u16x4*)&Gp_[c0];                                \
      d1 = *(const u16x4*)&Gp_[c0 + 128];                          \
      d2 = *(const u16x4*)&Gp_[c0 + 256]; }

#define GRU_STEP(IT, Gv0, Gv1, Gv2)                                         \
    {                                                                       \
        const int row_ = (IT) * 16 + l15;                                   \
        const bool upd_ = (t < dreg[IT]);                                   \
        bf16x8 af0 = *(const bf16x8*)&hbuf[cur][row_][0 * 32 + l4 * 8];     \
        bf16x8 af1 = *(const bf16x8*)&hbuf[cur][row_][1 * 32 + l4 * 8];     \
        bf16x8 af2 = *(const bf16x8*)&hbuf[cur][row_][2 * 32 + l4 * 8];     \
        bf16x8 af3 = *(const bf16x8*)&hbuf[cur][row_][3 * 32 + l4 * 8];     \
        f32x4 ar = fz, az = fz, an = fz;                                    \
        ar = mfma16(bfr[0][0], af0, ar); az = mfma16(bfr[1][0], af0, az);   \
        an = mfma16(bfr[2][0], af0, an);                                    \
        ar = mfma16(bfr[0][1], af1, ar); az = mfma16(bfr[1][1], af1, az);   \
        an = mfma16(bfr[2][1], af1, an);                                    \
        ar = mfma16(bfr[0][2], af2, ar); az = mfma16(bfr[1][2], af2, az);   \
        an = mfma16(bfr[2][2], af2, an);                                    \
        ar = mfma16(bfr[0][3], af3, ar); az = mfma16(bfr[1][3], af3, az);   \
        an = mfma16(bfr[2][3], af3, an);                                    \
        const u16x4 hold_ = *(const u16x4*)&hbuf[cur][row_][c0];            \
        u16x4 hnew_;                                                        \
        _Pragma("unroll")                                                   \
        for (int r = 0; r < 4; ++r) {                                       \
            const float rr = sigm(b2f(Gv0[r]) + ar[r]);                     \
            const float zz = sigm(b2f(Gv1[r]) + az[r]);                     \
            const float nn = tanh_fast(b2f(Gv2[r]) + rr * (an[r] + bnN[r]));\
            const float hv = (1.f - zz) * nn + zz * b2f(hold_[r]);          \
            hnew_[r] = upd_ ? f2b(hv) : hold_[r];                           \
        }                                                                   \
        *(u16x4*)&hbuf[1 - cur][row_][c0] = hnew_;                          \
    }

__global__ __attribute__((amdgpu_flat_work_group_size(512, 512), amdgpu_waves_per_eu(4, 8)))
void gru_kernel(const ushort* __restrict__ G,
                const float* __restrict__ Whh,
                const float* __restrict__ bhh,
                const int* __restrict__ nbr_idx,
                const int* __restrict__ deg,
                const int* __restrict__ perm,
                ushort* __restrict__ neigh) {
    __shared__ alignas(16) ushort hbuf[2][64][136];
    __shared__ alignas(16) int nbrs[64][8];
    __shared__ int degs[64];
    __shared__ int nid[64];

    const int tid = threadIdx.x;
    const int l   = tid & 63;
    const int l15 = l & 15;
    const int l4  = l >> 4;
    const int blockRow = (gridDim.x - 1 - blockIdx.x) * 64;  // high-deg first
    const int colbase = (tid >> 6) * 16;
    const int c0 = colbase + l4 * 4;

    if (tid < 64) nid[tid] = perm[blockRow + tid];
    {
        bf16x8 z = {0, 0, 0, 0, 0, 0, 0, 0};
        bf16x8* p = (bf16x8*)&hbuf[0][0][0];
        for (int i = tid; i < 64 * 136 / 8; i += 512) p[i] = z;
    }
    __syncthreads();
    nbrs[tid >> 3][tid & 7] = nbr_idx[(long)nid[tid >> 3] * 8 + (tid & 7)];
    if (tid < 64) degs[tid] = deg[nid[tid]];

    bf16x8 bfr[3][4];
#pragma unroll
    for (int g = 0; g < 3; ++g)
#pragma unroll
        for (int kt = 0; kt < 4; ++kt)
            bfr[g][kt] = ld8_f32(&Whh[(long)(g * 128 + colbase + l15) * 128 + kt * 32 + l4 * 8]);
    const f32x4 bnN = *(const f32x4*)&bhh[256 + c0];  // n-gate bias only
    __syncthreads();

    int dreg[4];
#pragma unroll
    for (int it = 0; it < 4; ++it) dreg[it] = degs[it * 16 + l15];
    int dmax = degs[l];
#pragma unroll
    for (int off = 32; off > 0; off >>= 1) dmax = max(dmax, __shfl_xor(dmax, off, 64));
    dmax = __builtin_amdgcn_readfirstlane(dmax);

    const f32x4 fz = {0.f, 0.f, 0.f, 0.f};
    u16x4 p00, p01, p02, p10, p11, p12;
    GLOAD(p00, p01, p02, l15, 0);
    GLOAD(p10, p11, p12, 16 + l15, 0);

    int cur = 0;
    for (int t = 0; t < dmax; ++t) {
        u16x4 q20, q21, q22, q30, q31, q32;
        GLOAD(q20, q21, q22, 32 + l15, t);
        GLOAD(q30, q31, q32, 48 + l15, t);
        GRU_STEP(0, p00, p01, p02);
        GRU_STEP(1, p10, p11, p12);
        if (t + 1 < dmax) {  // wave-uniform: skip dead last-step prefetch
            GLOAD(p00, p01, p02, l15, t + 1);
            GLOAD(p10, p11, p12, 16 + l15, t + 1);
        }
        GRU_STEP(2, q20, q21, q22);
        GRU_STEP(3, q30, q31, q32);
        __syncthreads();
        cur ^= 1;
    }
    for (int idx = tid; idx < 64 * 16; idx += 512) {
        const int row = idx >> 4, ch = idx & 15;
        bf16x8* dst = (bf16x8*)(neigh + (long)nid[row] * 128);
        dst[ch] = *(const bf16x8*)&hbuf[cur][row][ch * 8];
    }
}

// ---------------- fused e + softmax + segment sums -------------------------
// 1024 blocks x 256 thr (4 waves); block = 4 graphs = 80 rows.
__global__ __launch_bounds__(256) void seg_e_k(const ushort* __restrict__ rst,
                                               const float* __restrict__ Wu,
                                               const float2* __restrict__ ss2,
                                               const float* __restrict__ fvl,
                                               const float* __restrict__ We,
                                               const float* __restrict__ pw,
                                               ushort* __restrict__ s12) {
    __shared__ float epart[4][80];
    __shared__ float ash[80];
    const int tid = threadIdx.x;
    const int w   = tid >> 6;
    const int l   = tid & 63;
    const int l15 = l & 15;
    const int l4  = l >> 4;
    const int colbase = w * 32;
    const int rowblk = blockIdx.x * 80;

    bf16x8 bfr[2][4];
    float bv[2], Wec[2];
#pragma unroll
    for (int jl = 0; jl < 2; ++jl) {
        const int wrow = colbase + jl * 16 + l15;
        float fb = 0.f;
#pragma unroll
        for (int kt = 0; kt < 4; ++kt) {
            const float* wp = &Wu[(long)wrow * 128 + kt * 32 + l4 * 8];
            float4 a = *(const float4*)wp;
            float4 b4 = *(const float4*)(wp + 4);
            const float* s = (const float*)(ss2 + kt * 32 + l4 * 8);
            float4 s0 = *(const float4*)s, s1 = *(const float4*)(s + 4);
            float4 s2 = *(const float4*)(s + 8), s3 = *(const float4*)(s + 12);
            fb += s0.y * a.x + s0.w * a.y + s1.y * a.z + s1.w * a.w
                + s2.y * b4.x + s2.w * b4.y + s3.y * b4.z + s3.w * b4.w;
            a.x *= s0.x; a.y *= s0.z; a.z *= s1.x; a.w *= s1.z;
            b4.x *= s2.x; b4.y *= s2.z; b4.z *= s3.x; b4.w *= s3.z;
            bfr[jl][kt] = pack8(a, b4);
        }
        fb += __shfl_xor(fb, 16, 64);
        fb += __shfl_xor(fb, 32, 64);
        bv[jl] = fb;
        Wec[jl] = We[wrow];
    }

    const f32x4 fz = {0.f, 0.f, 0.f, 0.f};
#pragma unroll
    for (int it = 0; it < 5; ++it) {
        const int arow = rowblk + it * 16 + l15;
        bf16x8 afr[4];
#pragma unroll
        for (int kt = 0; kt < 4; ++kt)
            afr[kt] = ld8_bf(&rst[(long)arow * 128 + kt * 32 + l4 * 8]);
        f32x4 acc[2];
#pragma unroll
        for (int jl = 0; jl < 2; ++jl) {
            acc[jl] = fz;
#pragma unroll
            for (int kt = 0; kt < 4; ++kt)
                acc[jl] = mfma16(afr[kt], bfr[jl][kt], acc[jl]);
        }
        float ps[4] = {0.f, 0.f, 0.f, 0.f};
#pragma unroll
        for (int jl = 0; jl < 2; ++jl) {
            const int col = colbase + jl * 16 + l15;
#pragma unroll
            for (int r = 0; r < 4; ++r) {
                const long orow = rowblk + it * 16 + l4 * 4 + r;
                const float v = acc[jl][r] + bv[jl];
                const int bg = (int)orow / PP;
                ps[r] += sigm(v + fvl[(long)bg * 128 + col]) * Wec[jl];
            }
        }
#pragma unroll
        for (int r = 0; r < 4; ++r) {
#pragma unroll
            for (int off = 1; off < 16; off <<= 1)
                ps[r] += __shfl_xor(ps[r], off, 64);
        }
        if (l15 == 0) {
#pragma unroll
            for (int r = 0; r < 4; ++r)
                epart[w][it * 16 + l4 * 4 + r] = ps[r];
        }
    }
    __syncthreads();
    if (tid < 80)
        ash[tid] = epart[0][tid] + epart[1][tid] + epart[2][tid] + epart[3][tid];
    __syncthreads();
    if (tid < 4) {
        const int o = tid * PP;
        float m = -1e30f;
        for (int p = 0; p < PP; ++p) m = fmaxf(m, ash[o + p]);
        float sum = 0.f;
        for (int p = 0; p < PP; ++p) { ash[o + p] = __expf(ash[o + p] - m); sum += ash[o + p]; }
        const float inv = __fdividef(1.f, sum);
        for (int p = 0; p < PP; ++p) ash[o + p] *= inv;
    }
    __syncthreads();
    const int c = tid & 127;
    const float2 sc2 = ss2[c];
#pragma unroll
    for (int pass = 0; pass < 2; ++pass) {
        const int gl = pass * 2 + (tid >> 7);
        const int g = blockIdx.x * 4 + gl;
        float a1 = 0.f, a2 = 0.f;
#pragma unroll
        for (int p = 0; p < PP; ++p) {
            const int node = g * PP + p;
            const float hv = b2f(rst[(long)node * 128 + c]) * sc2.x + sc2.y;
            a1 += ash[gl * PP + p] * hv;
            a2 += pw[node] * hv;
        }
        s12[(long)g * 128 + c]        = f2b(a1);
        s12[(long)(BB + g) * 128 + c] = f2b(a2);
    }
}

// ---------------------------------------------------------------------------
extern "C" void kernel_launch(void* const* d_in, const int* in_sizes, int n_in,
                              void* d_out, int out_size, void* d_ws, size_t ws_size,
                              hipStream_t stream) {
    const float* feat    = (const float*)d_in[0];
    const float* intend  = (const float*)d_in[1];
    const float* pw      = (const float*)d_in[2];
    const int*   nbr_idx = (const int*)d_in[3];
    const int*   deg     = (const int*)d_in[4];
    const int*   last    = (const int*)d_in[5];
    const float* bn1_g   = (const float*)d_in[6];
    const float* bn1_b   = (const float*)d_in[7];
    const float* W_ih    = (const float*)d_in[8];
    const float* W_hh    = (const float*)d_in[9];
    const float* b_ih    = (const float*)d_in[10];
    const float* b_hh    = (const float*)d_in[11];
    const float* W_self  = (const float*)d_in[12];
    const float* W_neigh = (const float*)d_in[13];
    const float* bn2_g   = (const float*)d_in[14];
    const float* bn2_b   = (const float*)d_in[15];
    const float* Wu      = (const float*)d_in[16];
    const float* Wv      = (const float*)d_in[17];
    const float* bv      = (const float*)d_in[18];
    const float* Wi      = (const float*)d_in[19];
    const float* bi      = (const float*)d_in[20];
    const float* We      = (const float*)d_in[21];
    const float* Wout    = (const float*)d_in[22];
    float* out = (float*)d_out;
    char* ws = (char*)d_ws;

    // workspace layout (bytes)
    ushort* G     = (ushort*)(ws + 0L);              // 62,914,560  [N,384] bf16
    ushort* rst   = G;                               // alias (G dead after gru)
    ushort* neigh = (ushort*)(ws + 62914560L);       // 20,971,520
    float*  fvl   = (float*)(ws + 83886080L);        // 2,097,152
    ushort* s12   = (ushort*)(ws + 86310912L);       // 2,097,152
    float*  part1 = (float*)(ws + 88408064L);        // 655,360
    float*  part2 = (float*)(ws + 89063424L);        // 1,310,720
    int*    perm  = (int*)(ws + 90374144L);          // 327,680
    float2* ss1   = (float2*)(ws + 90701824L);       // 1,024
    float2* ss2   = (float2*)(ws + 90702848L);       // 1,024
    int*    blockHist = (int*)(ws + 90703872L);      // 320*9*4 = 11,520
    int*    blockBase = (int*)(ws + 90715392L);      // 11,520

    // ---- BN1 stats + degree hist (fused) ----
    stats_hist_k<<<960, 256, 0, stream>>>(feat, deg, part1, blockHist);
    // ---- BN1 finalize + bucket scan (fused) ----
    bnfinal_scan_k<<<129, 256, 0, stream>>>(part1, 640, bn1_g, bn1_b, ss1,
                                            blockHist, blockBase);
    // ---- scatter -> perm ----
    scatter_k<<<NBLK_H, 256, 0, stream>>>(deg, blockBase, perm);

    // ---- G = bn1(feat)@W_ih.T + b_ih + b_hh[rz-fold]  (4-wave, JT=6) ----
    gemm_bt<384, 4, 1, true, false, true, true, true, false, 0><<<1280, 256, 0, stream>>>(
        feat, nullptr, W_ih, nullptr, b_ih, b_hh, 256, ss1, nullptr,
        nullptr, G, nullptr, 0);

    // ---- ragged GRU (degree-sorted, high-deg first) -> neigh ----
    gru_kernel<<<1280, 512, 0, stream>>>(G, W_hh, b_hh, nbr_idx, deg, perm, neigh);

    // ---- rst = bn1(feat)@W_self.T + neigh@W_neigh.T  (+BN2-stats epilogue) ----
    gemm_bt<128, 4, 2, true, false, false, false, true, false, 2><<<1280, 256, 0, stream>>>(
        feat, neigh, W_self, W_neigh, nullptr, nullptr, 0, ss1, nullptr,
        nullptr, rst, part2, 1280);
    bnfinal_scan_k<<<128, 256, 0, stream>>>(part2, 1280, bn2_g, bn2_b, ss2,
                                            nullptr, nullptr);

    // ---- fvl = intend@Wv.T + bv + bn2(rst)[last]@Wi.T + bi  (f32) ----
    gemm_bt<128, 4, 2, true, true, true, true, false, true, 1><<<64, 256, 0, stream>>>(
        intend, rst, Wv, Wi, bv, bi, 128, nullptr, ss2,
        last, fvl, nullptr, 0);

    // ---- fused e + softmax + segment sums -> s12 ----
    seg_e_k<<<1024, 256, 0, stream>>>(rst, Wu, ss2, fvl, We, pw, s12);

    // ---- [rst_g; pos] = s12 @ Wout.T -> d_out (f32) ----
    gemm_bt<256, 4, 1, false, false, false, false, false, false, 1><<<128, 256, 0, stream>>>(
        s12, nullptr, Wout, nullptr, nullptr, nullptr, 0, nullptr, nullptr,
        nullptr, out, nullptr, 0);

    (void)in_sizes; (void)n_in; (void)out_size; (void)ws_size;
}